// Round 9
// baseline (701.253 us; speedup 1.0000x reference)
//
#include <hip/hip_runtime.h>

typedef unsigned short u16;
typedef __attribute__((ext_vector_type(8))) short short8;
typedef __attribute__((ext_vector_type(4))) float f32x4;
typedef __attribute__((ext_vector_type(16))) float f32x16;
typedef __attribute__((ext_vector_type(2))) unsigned int u32x2;

#define NPTS 1048576
#define TILES 64
#define NBLK (NPTS / (32 * TILES))   // 512 blocks
#define HPE 72    // 64-col buffer row stride (144 B, 16B-aligned)
#define HPB 264   // 256-col buffer row stride (528 B)
#define HPF 136   // 128-col buffer row stride (272 B)

__device__ __forceinline__ u16 f2b(float f) {
    return (u16)((__float_as_uint(f) + 0x8000u) >> 16);
}
#define INV2PI 0.15915494309189535f
__device__ __forceinline__ float sinrev(float t) {
    t = t - floorf(t);
    return __builtin_amdgcn_sinf(t);
}

// ---------------- weight convert(fp32->bf16) + transpose/pad prepass ----------------
// ws layout (bf16), WT[n][k] row-major in k:
//  WT1  @      0 : 256 x  64   (W1 63x256; k==63 = b1[n] bias fold, act col63=1.0)
//  WT2  @  16384 : 256 x 256
//  WT3  @  81920 : 256 x 256
//  WT4  @ 147456 :  16 x 256
//  WTc1 @ 151552 : 128 x  64   (Wc1 42x128; k==42 = bc1[n]; k>42 -> 0)
//  WTc2 @ 159744 :  16 x 128   (Wc2 128x3, n>=3 -> 0)
__global__ void prep_weights(const float* __restrict__ W1, const float* __restrict__ b1,
                             const float* __restrict__ W2,
                             const float* __restrict__ W3, const float* __restrict__ W4,
                             const float* __restrict__ Wc1, const float* __restrict__ bc1,
                             const float* __restrict__ Wc2,
                             u16* __restrict__ ws) {
    int i = blockIdx.x * 256 + threadIdx.x;
    if (i < 16384) { int n = i >> 6, k = i & 63;  ws[i]          = (k < 63) ? f2b(W1[k * 256 + n]) : f2b(b1[n]); return; }
    i -= 16384;
    if (i < 65536) { int n = i >> 8, k = i & 255; ws[16384 + i]  = f2b(W2[k * 256 + n]); return; }
    i -= 65536;
    if (i < 65536) { int n = i >> 8, k = i & 255; ws[81920 + i]  = f2b(W3[k * 256 + n]); return; }
    i -= 65536;
    if (i < 4096)  { int n = i >> 8, k = i & 255; ws[147456 + i] = f2b(W4[k * 16 + n]); return; }
    i -= 4096;
    if (i < 8192)  { int n = i >> 6, k = i & 63;
                     ws[151552 + i] = (k < 42) ? f2b(Wc1[k * 128 + n]) : ((k == 42) ? f2b(bc1[n]) : (u16)0); return; }
    i -= 8192;
    if (i < 2048)  { int n = i >> 7, k = i & 127; ws[159744 + i] = (n < 3) ? f2b(Wc2[k * 3 + n]) : (u16)0; return; }
}

// Epilogue for 32x32x16 (A=weights, B=acts): lane = batch row, regs = 16 neurons.
// reg r -> neuron (r&3)+8*(r>>2)+4*kh within [nbase,+32): packed b64 writes.
template <bool BIAS>
__device__ __forceinline__ void epi32(const f32x16& acc, u16* rowp, const float* bias,
                                      int nbase, int kh) {
#pragma unroll
    for (int g = 0; g < 4; ++g) {
        const int mq = nbase + 8 * g + 4 * kh;
        float v[4];
#pragma unroll
        for (int j = 0; j < 4; ++j) v[j] = acc[4 * g + j];
        if (BIAS) {
            const f32x4 bi = *(const f32x4*)(bias + mq);
#pragma unroll
            for (int j = 0; j < 4; ++j) v[j] += bi[j];
        }
#pragma unroll
        for (int j = 0; j < 4; ++j) v[j] = fmaxf(v[j], 0.f);
        unsigned int u[4];
#pragma unroll
        for (int j = 0; j < 4; ++j) u[j] = __float_as_uint(v[j]) + 0x8000u;
        u32x2 d;
        d.x = __builtin_amdgcn_perm(u[1], u[0], 0x07060302);
        d.y = __builtin_amdgcn_perm(u[3], u[2], 0x07060302);
        *(u32x2*)(rowp + mq) = d;
    }
}

// One 32-neuron-per-wave dense layer step: resident A-frags, LDS acts, relu epi.
template <int NKT, bool BIAS>
__device__ __forceinline__ void layer32(const short8* wr, const u16* src, int ss,
                                        u16* dst, int ds, const float* bias,
                                        int nbase, int ln, int kh) {
    f32x16 acc;
#pragma unroll
    for (int r = 0; r < 16; ++r) acc[r] = 0.f;
#pragma unroll
    for (int kt = 0; kt < NKT; ++kt) {
        const short8 bA = *(const short8*)(src + ln * ss + kt * 16 + kh * 8);
        acc = __builtin_amdgcn_mfma_f32_32x32x16_bf16(wr[kt], bA, acc, 0, 0, 0);
    }
    epi32<BIAS>(acc, dst + ln * ds, bias, nbase, kh);
}

// Persistent-weight, 3-phase software-pipelined fused MLP.
// 2 tiles in flight; per phase: one big MFMA layer + heterogeneous small tasks.
__global__ __launch_bounds__(512, 2) void ngp_fused(
    const float* __restrict__ pos, const float* __restrict__ dir, const u16* __restrict__ ws,
    const float* __restrict__ b2, const float* __restrict__ b3,
    const float* __restrict__ b4, const float* __restrict__ bc2,
    float* __restrict__ out) {
    __shared__ __align__(16) u16 sE[32][HPE];       // encode out (64c)
    __shared__ __align__(16) u16 sB[32][HPB];       // L1 out (256c)
    __shared__ __align__(16) u16 sC[32][HPB];       // L2 out (256c)
    __shared__ __align__(16) u16 sD[32][HPB];       // L3 out (256c)
    __shared__ __align__(16) u16 sG[2][32][HPE];    // color in (64c): dir-enc + feat
    __shared__ __align__(16) u16 sF[32][HPF];       // ch1 out (128c)
    const int t = threadIdx.x;
    const int lane = t & 63;
    const int w = t >> 6;
    const int ln = lane & 31, kh = lane >> 5;    // 32x32 frag coords
    const int lr = lane & 15, q = lane >> 4;     // 16x16 frag coords

    const u16* WT1  = ws;
    const u16* WT2  = ws + 16384;
    const u16* WT3  = ws + 81920;
    const u16* WT4  = ws + 147456;
    const u16* WTc1 = ws + 151552;
    const u16* WTc2 = ws + 159744;

    // ---- resident weight fragments (once per block) ----
    short8 w1r[4], w2r[16], w3r[16], wc1r[4];
    {
        const u16* p = WT1 + (size_t)(w * 32 + ln) * 64 + kh * 8;
#pragma unroll
        for (int kt = 0; kt < 4; ++kt) w1r[kt] = *(const short8*)(p + kt * 16);
    }
    {
        const u16* p = WT2 + (size_t)(w * 32 + ln) * 256 + kh * 8;
#pragma unroll
        for (int kt = 0; kt < 16; ++kt) w2r[kt] = *(const short8*)(p + kt * 16);
    }
    {
        const u16* p = WT3 + (size_t)(w * 32 + ln) * 256 + kh * 8;
#pragma unroll
        for (int kt = 0; kt < 16; ++kt) w3r[kt] = *(const short8*)(p + kt * 16);
    }
    if (w < 4) {
        const u16* p = WTc1 + (size_t)(w * 32 + ln) * 64 + kh * 8;
#pragma unroll
        for (int kt = 0; kt < 4; ++kt) wc1r[kt] = *(const short8*)(p + kt * 16);
    }

    for (int i = 0; i <= TILES + 1; ++i) {
        const bool doE = (i < TILES);               // enc/L1/L2 of tile i
        const bool doM = (i >= 1 && i <= TILES);    // L3/F/C of tile i-1
        const bool doH = (i >= 2);                  // head of tile i-2
        const long rbE = ((long)blockIdx.x * TILES + i) * 32;
        const long rbF = rbE - 32;
        const long rbH = rbE - 64;
        u16* sGe = &sG[i & 1][0][0];
        u16* sGf = &sG[(i - 1) & 1][0][0];

        // ================= Phase 1: E-loads -> L3(i-1) -> E(i) writes =================
        float e0 = 0.f, e1 = 0.f, e2 = 0.f;
        if (doE) {
            if (t < 256) {
                const long row = rbE + (t >> 3);
                e0 = pos[row * 3 + 0]; e1 = pos[row * 3 + 1]; e2 = pos[row * 3 + 2];
            } else if (((t - 256) & 7) < 6) {
                const long row = rbE + ((t - 256) >> 3);
                e0 = dir[row * 3 + 0]; e1 = dir[row * 3 + 1]; e2 = dir[row * 3 + 2];
            }
        }
        if (doM)
            layer32<16, true>(w3r, &sC[0][0], HPB, &sD[0][0], HPB, b3, w * 32, ln, kh);
        if (doE) {
            if (t < 256) {
                const int r = t >> 3, g = t & 7;
                const float xn[3] = {e0 * (1.f / 1.5f), e1 * (1.f / 1.5f), e2 * (1.f / 1.5f)};
                if (g < 5) {
#pragma unroll
                    for (int dd = 0; dd < 2; ++dd) {
                        const int d = 2 * g + dd;
                        const float sc = (float)(1 << d);
#pragma unroll
                        for (int c = 0; c < 3; ++c) {
                            float tv = xn[c] * sc * INV2PI;
                            sE[r][3 + d * 3 + c]  = f2b(sinrev(tv));
                            sE[r][33 + d * 3 + c] = f2b(sinrev(tv + 0.25f));
                        }
                    }
                } else if (g == 5) {
                    sE[r][0] = f2b(xn[0]); sE[r][1] = f2b(xn[1]); sE[r][2] = f2b(xn[2]);
                    sE[r][63] = 0x3F80;   // 1.0 -> b1 fold
                }
            } else {
                const int t2 = t - 256;
                const int r = t2 >> 3, g = t2 & 7;
                u16* gr = sGe + r * HPE;
                if (g < 6) {
                    const float nrm = sqrtf(e0 * e0 + e1 * e1 + e2 * e2);
                    const float inv = 1.f / fmaxf(nrm, 1e-12f);
                    const float dn[3] = {e0 * inv, e1 * inv, e2 * inv};
                    if (g < 4) {
                        const float sc = (float)(1 << g);
#pragma unroll
                        for (int c = 0; c < 3; ++c) {
                            float tv = dn[c] * sc * INV2PI;
                            gr[18 + g * 3 + c] = f2b(sinrev(tv));
                            gr[30 + g * 3 + c] = f2b(sinrev(tv + 0.25f));
                        }
                    } else if (g == 4) {
                        gr[15] = f2b(dn[0]); gr[16] = f2b(dn[1]); gr[17] = f2b(dn[2]);
                    } else {  // g == 5
                        gr[42] = 0x3F80;  // 1.0 -> bc1 fold
#pragma unroll
                        for (int c = 43; c < 50; ++c) gr[c] = 0;
                    }
                } else if (g == 6) {
#pragma unroll
                    for (int c = 50; c < 57; ++c) gr[c] = 0;
                } else {
#pragma unroll
                    for (int c = 57; c < 64; ++c) gr[c] = 0;
                }
            }
        }
        __syncthreads();

        // ======== Phase 2: W-streams -> L1(i) -> F(i-1) [w2,3] -> H(i-2) [w4,5] ========
        short8 f4[8];
        if (doM && (w == 2 || w == 3)) {
#pragma unroll
            for (int kt = 0; kt < 8; ++kt)
                f4[kt] = *(const short8*)(WT4 + lr * 256 + kt * 32 + q * 8);
        }
        short8 h2[4];
        if (doH && (w == 4 || w == 5)) {
#pragma unroll
            for (int kt = 0; kt < 4; ++kt)
                h2[kt] = *(const short8*)(WTc2 + lr * 128 + kt * 32 + q * 8);
        }
        if (doE)
            layer32<4, false>(w1r, &sE[0][0], HPE, &sB[0][0], HPB, nullptr, w * 32, ln, kh);
        if (doM && (w == 2 || w == 3)) {
            const int rbase = (w - 2) * 16;
            f32x4 acc = {0.f, 0.f, 0.f, 0.f};
#pragma unroll
            for (int kt = 0; kt < 8; ++kt) {
                const short8 aF = *(const short8*)&sD[rbase + lr][kt * 32 + q * 8];
                acc = __builtin_amdgcn_mfma_f32_16x16x32_bf16(aF, f4[kt], acc, 0, 0, 0);
            }
            const float bi = b4[lr];
#pragma unroll
            for (int r = 0; r < 4; ++r) {
                const float v = acc[r] + bi;
                const int gm = rbase + q * 4 + r;
                if (lr == 0)
                    out[3 * (long)NPTS + rbF + gm] = __expf(v - 1.f);
                else
                    sGf[gm * HPE + lr - 1] = f2b(v);   // feat -> cols 0..14
            }
        }
        if (doH && (w == 4 || w == 5)) {
            const int rbase = (w - 4) * 16;
            f32x4 acc = {0.f, 0.f, 0.f, 0.f};
#pragma unroll
            for (int kt = 0; kt < 4; ++kt) {
                const short8 aF = *(const short8*)&sF[rbase + lr][kt * 32 + q * 8];
                acc = __builtin_amdgcn_mfma_f32_16x16x32_bf16(aF, h2[kt], acc, 0, 0, 0);
            }
            if (lr < 3) {
                const float bi = bc2[lr];
#pragma unroll
                for (int r = 0; r < 4; ++r) {
                    const float v = acc[r] + bi;
                    const float sg = 1.f / (1.f + __expf(-v));
                    out[(rbH + rbase + q * 4 + r) * 3 + lr] = sg;
                }
            }
        }
        __syncthreads();

        // ================= Phase 3: L2(i) -> C(i-1) [waves 0-3] =================
        if (doE)
            layer32<16, true>(w2r, &sB[0][0], HPB, &sC[0][0], HPB, b2, w * 32, ln, kh);
        if (doM && w < 4)
            layer32<4, false>(wc1r, sGf, HPE, &sF[0][0], HPF, nullptr, w * 32, ln, kh);
        __syncthreads();
    }
}

extern "C" void kernel_launch(void* const* d_in, const int* in_sizes, int n_in,
                              void* d_out, int out_size, void* d_ws, size_t ws_size,
                              hipStream_t stream) {
    const float* pos = (const float*)d_in[0];
    const float* dir = (const float*)d_in[1];
    const float* W1  = (const float*)d_in[2];
    const float* b1  = (const float*)d_in[3];
    const float* W2  = (const float*)d_in[4];
    const float* b2  = (const float*)d_in[5];
    const float* W3  = (const float*)d_in[6];
    const float* b3  = (const float*)d_in[7];
    const float* W4  = (const float*)d_in[8];
    const float* b4  = (const float*)d_in[9];
    const float* Wc1 = (const float*)d_in[10];
    const float* bc1 = (const float*)d_in[11];
    const float* Wc2 = (const float*)d_in[12];
    const float* bc2 = (const float*)d_in[13];
    u16* ws   = (u16*)d_ws;
    float* out = (float*)d_out;

    prep_weights<<<633, 256, 0, stream>>>(W1, b1, W2, W3, W4, Wc1, bc1, Wc2, ws);
    ngp_fused<<<NBLK, 512, 0, stream>>>(pos, dir, ws, b2, b3, b4, bc2, out);
}

// Round 10
// 632.939 us; speedup vs baseline: 1.1079x; 1.1079x over previous
//
#include <hip/hip_runtime.h>

typedef unsigned short u16;
typedef __attribute__((ext_vector_type(8))) short short8;
typedef __attribute__((ext_vector_type(4))) float f32x4;
typedef __attribute__((ext_vector_type(16))) float f32x16;
typedef __attribute__((ext_vector_type(2))) unsigned int u32x2;

#define NPTS 1048576
#define TILES 128
#define NBLK (NPTS / (32 * TILES))   // 256 blocks = 1 per CU
#define HPE 72    // 64-col row stride (144 B)
#define HPB 264   // 256-col row stride (528 B)
#define HPF 136   // 128-col row stride (272 B)

__device__ __forceinline__ u16 f2b(float f) {
    return (u16)((__float_as_uint(f) + 0x8000u) >> 16);
}
#define INV2PI 0.15915494309189535f
__device__ __forceinline__ float sinrev(float t) {
    t = t - floorf(t);
    return __builtin_amdgcn_sinf(t);
}

// ---------------- weight convert(fp32->bf16) + transpose/pad prepass ----------------
// ws layout (bf16), WT[n][k] row-major in k:
//  WT1  @      0 : 256 x  64   (W1 63x256; k==63 = b1[n] bias fold, act col63=1.0)
//  WT2  @  16384 : 256 x 256
//  WT3  @  81920 : 256 x 256
//  WT4  @ 147456 :  16 x 256
//  WTc1 @ 151552 : 128 x  64   (Wc1 42x128; k==42 = bc1[n]; k>42 -> 0)
//  WTc2 @ 159744 :  16 x 128   (Wc2 128x3, n>=3 -> 0)
__global__ void prep_weights(const float* __restrict__ W1, const float* __restrict__ b1,
                             const float* __restrict__ W2,
                             const float* __restrict__ W3, const float* __restrict__ W4,
                             const float* __restrict__ Wc1, const float* __restrict__ bc1,
                             const float* __restrict__ Wc2,
                             u16* __restrict__ ws) {
    int i = blockIdx.x * 256 + threadIdx.x;
    if (i < 16384) { int n = i >> 6, k = i & 63;  ws[i]          = (k < 63) ? f2b(W1[k * 256 + n]) : f2b(b1[n]); return; }
    i -= 16384;
    if (i < 65536) { int n = i >> 8, k = i & 255; ws[16384 + i]  = f2b(W2[k * 256 + n]); return; }
    i -= 65536;
    if (i < 65536) { int n = i >> 8, k = i & 255; ws[81920 + i]  = f2b(W3[k * 256 + n]); return; }
    i -= 65536;
    if (i < 4096)  { int n = i >> 8, k = i & 255; ws[147456 + i] = f2b(W4[k * 16 + n]); return; }
    i -= 4096;
    if (i < 8192)  { int n = i >> 6, k = i & 63;
                     ws[151552 + i] = (k < 42) ? f2b(Wc1[k * 128 + n]) : ((k == 42) ? f2b(bc1[n]) : (u16)0); return; }
    i -= 8192;
    if (i < 2048)  { int n = i >> 7, k = i & 127; ws[159744 + i] = (n < 3) ? f2b(Wc2[k * 3 + n]) : (u16)0; return; }
}

// Epilogue for 32x32x16 (A=weights, B=acts): lane = batch row, regs = 16 neurons.
template <bool BIAS>
__device__ __forceinline__ void epi32(const f32x16& acc, u16* rowp, const float* bias,
                                      int nbase, int kh) {
#pragma unroll
    for (int g = 0; g < 4; ++g) {
        const int mq = nbase + 8 * g + 4 * kh;
        float v[4];
#pragma unroll
        for (int j = 0; j < 4; ++j) v[j] = acc[4 * g + j];
        if (BIAS) {
            const f32x4 bi = *(const f32x4*)(bias + mq);
#pragma unroll
            for (int j = 0; j < 4; ++j) v[j] += bi[j];
        }
#pragma unroll
        for (int j = 0; j < 4; ++j) v[j] = fmaxf(v[j], 0.f);
        unsigned int u[4];
#pragma unroll
        for (int j = 0; j < 4; ++j) u[j] = __float_as_uint(v[j]) + 0x8000u;
        u32x2 d;
        d.x = __builtin_amdgcn_perm(u[1], u[0], 0x07060302);
        d.y = __builtin_amdgcn_perm(u[3], u[2], 0x07060302);
        *(u32x2*)(rowp + mq) = d;
    }
}

template <int NKT, bool BIAS>
__device__ __forceinline__ void layer32(const short8* wr, const u16* src, int ss,
                                        u16* dst, int ds, const float* bias,
                                        int nbase, int ln, int kh) {
    f32x16 acc;
#pragma unroll
    for (int r = 0; r < 16; ++r) acc[r] = 0.f;
#pragma unroll
    for (int kt = 0; kt < NKT; ++kt) {
        const short8 bA = *(const short8*)(src + ln * ss + kt * 16 + kh * 8);
        acc = __builtin_amdgcn_mfma_f32_32x32x16_bf16(wr[kt], bA, acc, 0, 0, 0);
    }
    epi32<BIAS>(acc, dst + ln * ds, bias, nbase, kh);
}

// Producer/consumer wave-specialized fused MLP: 16 waves (4/SIMD).
// Front waves 0-7 (resident W1,W2): enc(i) -> L1(i) -> L2(i).
// Back waves 8-15 (resident W3, Wc1): L3(i-1) -> L4(i-1)/head(i-2) -> ch1(i-1).
__global__ __launch_bounds__(1024, 4) void ngp_fused(
    const float* __restrict__ pos, const float* __restrict__ dir, const u16* __restrict__ ws,
    const float* __restrict__ b2, const float* __restrict__ b3,
    const float* __restrict__ b4, const float* __restrict__ bc2,
    float* __restrict__ out) {
    __shared__ __align__(16) u16 sE[32][HPE];       // encode out (64c)
    __shared__ __align__(16) u16 sB[32][HPB];       // L1 out (256c)
    __shared__ __align__(16) u16 sC[32][HPB];       // L2 out (256c)
    __shared__ __align__(16) u16 sD[32][HPB];       // L3 out (256c)
    __shared__ __align__(16) u16 sG[2][32][HPE];    // color in (64c)
    __shared__ __align__(16) u16 sF[32][HPF];       // ch1 out (128c)
    const int t = threadIdx.x;
    const int lane = t & 63;
    const int w = t >> 6;                        // 16 waves
    const int bw = w - 8;                        // back-wave index (valid w>=8)
    const int ln = lane & 31, kh = lane >> 5;    // 32x32 frag coords
    const int lr = lane & 15, q = lane >> 4;     // 16x16 frag coords

    const u16* WT1  = ws;
    const u16* WT2  = ws + 16384;
    const u16* WT3  = ws + 81920;
    const u16* WT4  = ws + 147456;
    const u16* WTc1 = ws + 151552;
    const u16* WTc2 = ws + 159744;

    // ---- resident weights, unioned across roles (shared physical regs) ----
    short8 wrA[16], wrB[4];
    {
        const u16* pA = (w < 8) ? WT2 + (size_t)(w * 32 + ln) * 256 + kh * 8
                                : WT3 + (size_t)(bw * 32 + ln) * 256 + kh * 8;
#pragma unroll
        for (int kt = 0; kt < 16; ++kt) wrA[kt] = *(const short8*)(pA + kt * 16);
        const u16* pB = (w < 8)  ? WT1 + (size_t)(w * 32 + ln) * 64 + kh * 8
                      : (bw < 4) ? WTc1 + (size_t)(bw * 32 + ln) * 64 + kh * 8
                                 : WT1 + (size_t)ln * 64 + kh * 8;   // dummy (unused)
#pragma unroll
        for (int kt = 0; kt < 4; ++kt) wrB[kt] = *(const short8*)(pB + kt * 16);
    }

    for (int i = 0; i <= TILES + 1; ++i) {
        const bool doE = (i < TILES);
        const bool doM = (i >= 1 && i <= TILES);
        const bool doH = (i >= 2);
        const long rbE = ((long)blockIdx.x * TILES + i) * 32;
        const long rbM = rbE - 32;
        const long rbH = rbE - 64;
        u16* sGe = &sG[i & 1][0][0];           // dir-enc(i)
        u16* sGf = &sG[(i + 1) & 1][0][0];     // feat/ch1 of tile i-1

        // ========== Phase 1: enc(i) [front] | L3(i-1) [back] ==========
        if (doE && t < 512) {
            if (t < 256) {
                const int r = t >> 3, g = t & 7;
                const long row = rbE + r;
                float xn[3];
#pragma unroll
                for (int c = 0; c < 3; ++c) xn[c] = pos[row * 3 + c] * (1.0f / 1.5f);
                if (g < 5) {
#pragma unroll
                    for (int dd = 0; dd < 2; ++dd) {
                        const int d = 2 * g + dd;
                        const float sc = (float)(1 << d);
#pragma unroll
                        for (int c = 0; c < 3; ++c) {
                            float tv = xn[c] * sc * INV2PI;
                            sE[r][3 + d * 3 + c]  = f2b(sinrev(tv));
                            sE[r][33 + d * 3 + c] = f2b(sinrev(tv + 0.25f));
                        }
                    }
                } else if (g == 5) {
                    sE[r][0] = f2b(xn[0]); sE[r][1] = f2b(xn[1]); sE[r][2] = f2b(xn[2]);
                    sE[r][63] = 0x3F80;   // 1.0 -> b1 fold
                }
            } else {
                const int t2 = t - 256;
                const int r = t2 >> 3, g = t2 & 7;
                const long row = rbE + r;
                u16* gr = sGe + r * HPE;
                const float dx = dir[row * 3 + 0];
                const float dy = dir[row * 3 + 1];
                const float dz = dir[row * 3 + 2];
                if (g < 6) {
                    const float nrm = sqrtf(dx * dx + dy * dy + dz * dz);
                    const float inv = 1.f / fmaxf(nrm, 1e-12f);
                    const float dn[3] = {dx * inv, dy * inv, dz * inv};
                    if (g < 4) {
                        const float sc = (float)(1 << g);
#pragma unroll
                        for (int c = 0; c < 3; ++c) {
                            float tv = dn[c] * sc * INV2PI;
                            gr[18 + g * 3 + c] = f2b(sinrev(tv));
                            gr[30 + g * 3 + c] = f2b(sinrev(tv + 0.25f));
                        }
                    } else if (g == 4) {
                        gr[15] = f2b(dn[0]); gr[16] = f2b(dn[1]); gr[17] = f2b(dn[2]);
                    } else {
                        gr[42] = 0x3F80;  // 1.0 -> bc1 fold
#pragma unroll
                        for (int c = 43; c < 50; ++c) gr[c] = 0;
                    }
                } else if (g == 6) {
#pragma unroll
                    for (int c = 50; c < 57; ++c) gr[c] = 0;
                } else {
#pragma unroll
                    for (int c = 57; c < 64; ++c) gr[c] = 0;
                }
            }
        }
        if (doM && w >= 8)
            layer32<16, true>(wrA, &sC[0][0], HPB, &sD[0][0], HPB, b3, bw * 32, ln, kh);
        __syncthreads();

        // ========== Phase 2: L1(i) [front] | L4(i-1) [bw4,5] | head(i-2) [bw6,7] ==========
        if (doE && w < 8)
            layer32<4, false>(wrB, &sE[0][0], HPE, &sB[0][0], HPB, nullptr, w * 32, ln, kh);
        if (doM && w >= 8 && (bw == 4 || bw == 5)) {
            const int rbase = (bw - 4) * 16;
            f32x4 acc = {0.f, 0.f, 0.f, 0.f};
#pragma unroll
            for (int kt = 0; kt < 8; ++kt) {
                const short8 aF = *(const short8*)&sD[rbase + lr][kt * 32 + q * 8];
                const short8 bF = *(const short8*)(WT4 + lr * 256 + kt * 32 + q * 8);
                acc = __builtin_amdgcn_mfma_f32_16x16x32_bf16(aF, bF, acc, 0, 0, 0);
            }
            const float bi = b4[lr];
#pragma unroll
            for (int r = 0; r < 4; ++r) {
                const float v = acc[r] + bi;
                const int gm = rbase + q * 4 + r;
                if (lr == 0)
                    out[3 * (long)NPTS + rbM + gm] = __expf(v - 1.f);
                else
                    sGf[gm * HPE + lr - 1] = f2b(v);   // feat -> cols 0..14
            }
        }
        if (doH && w >= 8 && (bw == 6 || bw == 7)) {
            const int rbase = (bw - 6) * 16;
            f32x4 acc = {0.f, 0.f, 0.f, 0.f};
#pragma unroll
            for (int kt = 0; kt < 4; ++kt) {
                const short8 aF = *(const short8*)&sF[rbase + lr][kt * 32 + q * 8];
                const short8 bF = *(const short8*)(WTc2 + lr * 128 + kt * 32 + q * 8);
                acc = __builtin_amdgcn_mfma_f32_16x16x32_bf16(aF, bF, acc, 0, 0, 0);
            }
            if (lr < 3) {
                const float bi = bc2[lr];
#pragma unroll
                for (int r = 0; r < 4; ++r) {
                    const float v = acc[r] + bi;
                    const float sg = 1.f / (1.f + __expf(-v));
                    out[(rbH + rbase + q * 4 + r) * 3 + lr] = sg;
                }
            }
        }
        __syncthreads();

        // ========== Phase 3: L2(i) [front] | ch1(i-1) [bw0-3] ==========
        if (doE && w < 8)
            layer32<16, true>(wrA, &sB[0][0], HPB, &sC[0][0], HPB, b2, w * 32, ln, kh);
        if (doM && w >= 8 && bw < 4)
            layer32<4, false>(wrB, sGf, HPE, &sF[0][0], HPF, nullptr, bw * 32, ln, kh);
        __syncthreads();
    }
}

extern "C" void kernel_launch(void* const* d_in, const int* in_sizes, int n_in,
                              void* d_out, int out_size, void* d_ws, size_t ws_size,
                              hipStream_t stream) {
    const float* pos = (const float*)d_in[0];
    const float* dir = (const float*)d_in[1];
    const float* W1  = (const float*)d_in[2];
    const float* b1  = (const float*)d_in[3];
    const float* W2  = (const float*)d_in[4];
    const float* b2  = (const float*)d_in[5];
    const float* W3  = (const float*)d_in[6];
    const float* b3  = (const float*)d_in[7];
    const float* W4  = (const float*)d_in[8];
    const float* b4  = (const float*)d_in[9];
    const float* Wc1 = (const float*)d_in[10];
    const float* bc1 = (const float*)d_in[11];
    const float* Wc2 = (const float*)d_in[12];
    const float* bc2 = (const float*)d_in[13];
    u16* ws   = (u16*)d_ws;
    float* out = (float*)d_out;

    prep_weights<<<633, 256, 0, stream>>>(W1, b1, W2, W3, W4, Wc1, bc1, Wc2, ws);
    ngp_fused<<<NBLK, 1024, 0, stream>>>(pos, dir, ws, b2, b3, b4, bc2, out);
}